// Round 4
// baseline (2932.438 us; speedup 1.0000x reference)
//
#include <hip/hip_runtime.h>

#define D_MODEL 1024
#define NH 16
#define DK 64
#define DFF 4096
#define SEQ 2048
#define BATCH 4
#define NROWS (BATCH*SEQ)   // 8192
#define CHUNK 2048          // FFN row-chunk
#define NCHUNK (NROWS/CHUNK)

typedef short bf16x8 __attribute__((ext_vector_type(8)));
typedef float f32x4 __attribute__((ext_vector_type(4)));

__device__ __forceinline__ float bf2f(unsigned short u){
  union { float f; unsigned int i; } x; x.i = ((unsigned int)u) << 16; return x.f;
}
__device__ __forceinline__ unsigned short f2bf(float f){
  union { float f; unsigned int i; } x; x.f = f;
  unsigned int r = x.i + 0x7fffu + ((x.i >> 16) & 1u);
  return (unsigned short)(r >> 16);
}

// ---------------- LayerNorm: fp32 in -> bf16 out, one block per row of 1024 ----
// torch variant: unbiased std (ddof=1), eps added to std (not var)
__global__ __launch_bounds__(256) void ln_kernel(const float* __restrict__ in,
    const float* __restrict__ gam, const float* __restrict__ bet,
    unsigned short* __restrict__ out)
{
  const int row = blockIdx.x, t = threadIdx.x;
  const int base = t * 4;
  float4 raw = *(const float4*)(in + (size_t)row * D_MODEL + base);
  float v[4] = { raw.x, raw.y, raw.z, raw.w };
  float s  = v[0] + v[1] + v[2] + v[3];
  float s2 = v[0]*v[0] + v[1]*v[1] + v[2]*v[2] + v[3]*v[3];
  #pragma unroll
  for (int off = 32; off > 0; off >>= 1) {
    s  += __shfl_down(s,  off);
    s2 += __shfl_down(s2, off);
  }
  __shared__ float red[10];
  const int wid = t >> 6, lane = t & 63;
  if (lane == 0) { red[wid] = s; red[4 + wid] = s2; }
  __syncthreads();
  if (t == 0) {
    float ts  = red[0] + red[1] + red[2] + red[3];
    float ts2 = red[4] + red[5] + red[6] + red[7];
    float mean = ts * (1.0f / D_MODEL);
    float var  = (ts2 - (float)D_MODEL * mean * mean) * (1.0f / (D_MODEL - 1));
    var = fmaxf(var, 0.0f);
    red[8] = mean;
    red[9] = 1.0f / (sqrtf(var) + 1e-6f);
  }
  __syncthreads();
  const float mean = red[8], inv = red[9];
  float4 g4 = *(const float4*)(gam + base);
  float4 b4 = *(const float4*)(bet + base);
  union { int2 v; unsigned short u[4]; } o;
  o.u[0] = f2bf(g4.x * (v[0] - mean) * inv + b4.x);
  o.u[1] = f2bf(g4.y * (v[1] - mean) * inv + b4.y);
  o.u[2] = f2bf(g4.z * (v[2] - mean) * inv + b4.z);
  o.u[3] = f2bf(g4.w * (v[3] - mean) * inv + b4.w);
  *(int2*)(out + (size_t)row * D_MODEL + base) = o.v;
}

// ---------------- GEMM: C[m,n] = sum_k A[m,k] * Bw[n,k]  (+ epilogue) ----------
// A bf16 [M,K]; Bw fp32 [N,K] converted to bf16 during LDS staging.
// 128x128 tile, BK=32, 4 waves (2x2), each wave 64x64 via 4x4 mfma_16x16x32_bf16.
__global__ __launch_bounds__(256) void gemm_bt(
    const unsigned short* __restrict__ A,   // [M,K] bf16
    const float* __restrict__ Bw,           // [N,K] fp32
    int K, int N,
    const float* __restrict__ bias,    // [N] fp32 or null
    int relu,
    const float* __restrict__ residf,  // [M,N] fp32 or null
    unsigned short* __restrict__ outb, // [M,N] bf16 or null
    float* __restrict__ outf)          // [M,N] fp32 or null
{
  __shared__ short sA[128 * 32];
  __shared__ short sB[128 * 32];
  const int t = threadIdx.x;
  const int tileN = blockIdx.x * 128;
  const int tileM = blockIdx.y * 128;
  const int wid = t >> 6, lane = t & 63;
  const int wM = (wid >> 1) * 64, wN = (wid & 1) * 64;
  const int quad = lane >> 4, lrow = lane & 15;

  f32x4 acc[4][4] = {};

  for (int k0 = 0; k0 < K; k0 += 32) {
    #pragma unroll
    for (int it = 0; it < 2; it++) {
      int seg = it * 256 + t;            // 512 x 8-element segments per tile
      int row = seg >> 2, c8 = (seg & 3) * 8;
      // A: bf16, direct 16B copy
      *(int4*)&sA[row * 32 + c8] = *(const int4*)(A + (size_t)(tileM + row) * K + k0 + c8);
      // B: fp32 -> cvt -> bf16
      const float* bsrc = Bw + (size_t)(tileN + row) * K + k0 + c8;
      float4 f0 = *(const float4*)bsrc;
      float4 f1 = *(const float4*)(bsrc + 4);
      union { int4 v; unsigned short u[8]; } bb;
      bb.u[0] = f2bf(f0.x); bb.u[1] = f2bf(f0.y); bb.u[2] = f2bf(f0.z); bb.u[3] = f2bf(f0.w);
      bb.u[4] = f2bf(f1.x); bb.u[5] = f2bf(f1.y); bb.u[6] = f2bf(f1.z); bb.u[7] = f2bf(f1.w);
      *(int4*)&sB[row * 32 + c8] = bb.v;
    }
    __syncthreads();
    bf16x8 af[4], bfr[4];
    #pragma unroll
    for (int i = 0; i < 4; i++) {
      af[i]  = *(const bf16x8*)&sA[(wM + i * 16 + lrow) * 32 + quad * 8];
      bfr[i] = *(const bf16x8*)&sB[(wN + i * 16 + lrow) * 32 + quad * 8];
    }
    #pragma unroll
    for (int i = 0; i < 4; i++)
      #pragma unroll
      for (int j = 0; j < 4; j++)
        acc[i][j] = __builtin_amdgcn_mfma_f32_16x16x32_bf16(af[i], bfr[j], acc[i][j], 0, 0, 0);
    __syncthreads();
  }

  #pragma unroll
  for (int i = 0; i < 4; i++) {
    #pragma unroll
    for (int j = 0; j < 4; j++) {
      const int col = tileN + wN + j * 16 + lrow;
      const float bv = bias ? bias[col] : 0.0f;
      #pragma unroll
      for (int r = 0; r < 4; r++) {
        const int rowg = tileM + wM + i * 16 + quad * 4 + r;
        float val = acc[i][j][r] + bv;
        if (relu) val = fmaxf(val, 0.0f);
        const size_t idx = (size_t)rowg * N + col;
        if (residf) val += residf[idx];
        if (outf) outf[idx] = val;
        if (outb) outb[idx] = f2bf(val);
      }
    }
  }
}

// ---------------- Flash attention (vector ALU, online softmax) -----------------
// One block per (b, h, 32-query tile). bf16 Q/K/V, fp32 LDS tiles, K-tiles of 32.
// Og may alias Qg: each block reads exactly the Q rows/cols it writes (at end).
#define QT 32
__global__ __launch_bounds__(256) void attn_kernel(
    const unsigned short* __restrict__ Qg,
    const unsigned short* __restrict__ Kg,
    const unsigned short* __restrict__ Vg,
    const int* __restrict__ mask,   // [B*S]
    unsigned short* __restrict__ Og)
{
  const int bid = blockIdx.x;
  const int nqt = SEQ / QT;           // 64
  const int b  = bid / (NH * nqt);
  const int h  = (bid / nqt) % NH;
  const int q0 = (bid % nqt) * QT;

  __shared__ float Qs[QT][68];
  __shared__ float Ks[QT][68];
  __shared__ float Vs[QT][68];
  __shared__ float Ps[QT][33];
  __shared__ float mrow[QT], lrow[QT], arow[QT];
  __shared__ int   msk[QT];

  const int t  = threadIdx.x;
  const int qi = t >> 3;              // 0..31
  const int dg = (t & 7) * 8;         // 0..56
  const int kb = t & 7;               // key sub-group

  {
    size_t gidx = ((size_t)(b * SEQ + q0 + qi) * D_MODEL) + h * DK + dg;
    union { int4 v; unsigned short u[8]; } raw;
    raw.v = *(const int4*)(Qg + gidx);
    #pragma unroll
    for (int i = 0; i < 8; i++) Qs[qi][dg + i] = bf2f(raw.u[i]) * 0.125f; // 1/sqrt(64)
  }
  if (t < QT) { mrow[t] = -1e30f; lrow[t] = 0.0f; }
  float o[8];
  #pragma unroll
  for (int i = 0; i < 8; i++) o[i] = 0.0f;
  __syncthreads();

  for (int kt = 0; kt < SEQ; kt += QT) {
    {
      size_t gidx = ((size_t)(b * SEQ + kt + qi) * D_MODEL) + h * DK + dg;
      union { int4 v; unsigned short u[8]; } kraw, vraw;
      kraw.v = *(const int4*)(Kg + gidx);
      vraw.v = *(const int4*)(Vg + gidx);
      #pragma unroll
      for (int i = 0; i < 8; i++) { Ks[qi][dg + i] = bf2f(kraw.u[i]); Vs[qi][dg + i] = bf2f(vraw.u[i]); }
    }
    if (t < QT) msk[t] = mask[b * SEQ + kt + t];
    __syncthreads();

    // scores: each thread -> (qi, keys kb, kb+8, kb+16, kb+24)
    float sc[4] = {0.f, 0.f, 0.f, 0.f};
    #pragma unroll 4
    for (int d = 0; d < DK; d += 4) {
      float4 qv = *(const float4*)&Qs[qi][d];
      #pragma unroll
      for (int j = 0; j < 4; j++) {
        float4 kv = *(const float4*)&Ks[kb + j * 8][d];
        sc[j] += qv.x * kv.x + qv.y * kv.y + qv.z * kv.z + qv.w * kv.w;
      }
    }
    #pragma unroll
    for (int j = 0; j < 4; j++)
      Ps[qi][kb + j * 8] = msk[kb + j * 8] ? sc[j] : -1e9f;
    __syncthreads();

    // online softmax, one thread per query row
    if (t < QT) {
      float m = mrow[t], tm = -1e30f;
      #pragma unroll 8
      for (int j = 0; j < QT; j++) tm = fmaxf(tm, Ps[t][j]);
      float mn = fmaxf(m, tm);
      float a  = __expf(m - mn);
      float ls = 0.0f;
      #pragma unroll 8
      for (int j = 0; j < QT; j++) { float p = __expf(Ps[t][j] - mn); Ps[t][j] = p; ls += p; }
      lrow[t] = lrow[t] * a + ls;
      mrow[t] = mn;
      arow[t] = a;
    }
    __syncthreads();

    // PV accumulate
    {
      float a = arow[qi];
      #pragma unroll
      for (int i = 0; i < 8; i++) o[i] *= a;
      for (int kj = 0; kj < QT; kj++) {
        float p = Ps[qi][kj];
        float4 v0 = *(const float4*)&Vs[kj][dg];
        float4 v1 = *(const float4*)&Vs[kj][dg + 4];
        o[0] += p * v0.x; o[1] += p * v0.y; o[2] += p * v0.z; o[3] += p * v0.w;
        o[4] += p * v1.x; o[5] += p * v1.y; o[6] += p * v1.z; o[7] += p * v1.w;
      }
    }
    __syncthreads();
  }

  const float linv = 1.0f / lrow[qi];
  union { int4 v; unsigned short u[8]; } ob;
  #pragma unroll
  for (int i = 0; i < 8; i++) ob.u[i] = f2bf(o[i] * linv);
  size_t gidx = ((size_t)(b * SEQ + q0 + qi) * D_MODEL) + h * DK + dg;
  *(int4*)(Og + gidx) = ob.v;
}

// ---------------- launch ----------------
// fp32 inputs / fp32 output. Internal bf16 for MFMA operands.
// Workspace high-water 48MB:  q [0,16)  k [16,32)  v [32,48)
//   ln1 (bf16) lives in d_out's first 16MB (dead before o-proj overwrites d_out)
//   attn output in-place over q; ln2 reuses q; FFN hidden chunk reuses k.
//   x1 (fp32) lives in d_out; FFN2 adds residual in-place per chunk.
extern "C" void kernel_launch(void* const* d_in, const int* in_sizes, int n_in,
                              void* d_out, int out_size, void* d_ws, size_t ws_size,
                              hipStream_t stream)
{
  (void)in_sizes; (void)n_in; (void)out_size; (void)ws_size;
  const float* x   = (const float*)d_in[0];
  const int*   msk = (const int*)d_in[1];
  const float* w_q = (const float*)d_in[2];
  const float* w_k = (const float*)d_in[3];
  const float* w_v = (const float*)d_in[4];
  const float* w_o = (const float*)d_in[5];
  const float* w1  = (const float*)d_in[6];
  const float* b1  = (const float*)d_in[7];
  const float* w2  = (const float*)d_in[8];
  const float* b2  = (const float*)d_in[9];
  const float* g1  = (const float*)d_in[10];
  const float* be1 = (const float*)d_in[11];
  const float* g2  = (const float*)d_in[12];
  const float* be2 = (const float*)d_in[13];
  float* outf = (float*)d_out;

  char* ws = (char*)d_ws;
  const size_t MB = 1024 * 1024;
  unsigned short* q_b  = (unsigned short*)(ws + 0);        // 16MB, -> attn out (ao)
  unsigned short* k_b  = (unsigned short*)(ws + 16 * MB);  // 16MB, -> FFN hidden chunk
  unsigned short* v_b  = (unsigned short*)(ws + 32 * MB);  // 16MB
  unsigned short* ln1b = (unsigned short*)d_out;           // 16MB of d_out (bf16)
  unsigned short* ln2b = q_b;                              // reuse after o-proj
  unsigned short* hffc = k_b;                              // reuse after attention

  dim3 blk(256);
  dim3 gN1024(D_MODEL / 128, NROWS / 128);  // (8, 64)

  // LN1: x (fp32) -> ln1b (bf16, in d_out)
  ln_kernel<<<NROWS, blk, 0, stream>>>(x, g1, be1, ln1b);
  // Q, K, V projections (A bf16, B fp32-cvt)
  gemm_bt<<<gN1024, blk, 0, stream>>>(ln1b, w_q, D_MODEL, D_MODEL, nullptr, 0, nullptr, q_b, nullptr);
  gemm_bt<<<gN1024, blk, 0, stream>>>(ln1b, w_k, D_MODEL, D_MODEL, nullptr, 0, nullptr, k_b, nullptr);
  gemm_bt<<<gN1024, blk, 0, stream>>>(ln1b, w_v, D_MODEL, D_MODEL, nullptr, 0, nullptr, v_b, nullptr);
  // attention (output in-place over q)
  attn_kernel<<<BATCH * NH * (SEQ / QT), blk, 0, stream>>>(q_b, k_b, v_b, msk, q_b);
  // output projection + residual (x fp32) -> x1 = d_out (fp32)
  gemm_bt<<<gN1024, blk, 0, stream>>>(q_b, w_o, D_MODEL, D_MODEL, nullptr, 0, x, nullptr, outf);
  // LN2: x1 (fp32) -> ln2b (bf16)
  ln_kernel<<<NROWS, blk, 0, stream>>>(outf, g2, be2, ln2b);
  // FFN, M-chunked (hidden chunk reuses k region)
  for (int c = 0; c < NCHUNK; c++) {
    const size_t ro = (size_t)c * CHUNK;
    dim3 g1c(DFF / 128,     CHUNK / 128);   // (32, 16)
    dim3 g2c(D_MODEL / 128, CHUNK / 128);   // (8, 16)
    // FFN1: relu(ln2 @ w1^T + b1) -> hffc (bf16)
    gemm_bt<<<g1c, blk, 0, stream>>>(ln2b + ro * D_MODEL, w1, D_MODEL, DFF, b1, 1, nullptr, hffc, nullptr);
    // FFN2: x1 + hffc @ w2^T + b2 -> d_out rows (in-place residual)
    gemm_bt<<<g2c, blk, 0, stream>>>(hffc, w2, DFF, D_MODEL, b2, 0,
                                     outf + ro * D_MODEL, nullptr, outf + ro * D_MODEL);
  }
}

// Round 5
// 1111.674 us; speedup vs baseline: 2.6379x; 2.6379x over previous
//
#include <hip/hip_runtime.h>

#define D_MODEL 1024
#define NH 16
#define DK 64
#define DFF 4096
#define SEQ 2048
#define BATCH 4
#define NROWS (BATCH*SEQ)   // 8192
#define CHUNK 2048          // FFN row-chunk
#define NCHUNK (NROWS/CHUNK)

typedef short bf16x8 __attribute__((ext_vector_type(8)));
typedef float f32x4 __attribute__((ext_vector_type(4)));

__device__ __forceinline__ float bf2f(unsigned short u){
  union { float f; unsigned int i; } x; x.i = ((unsigned int)u) << 16; return x.f;
}
__device__ __forceinline__ unsigned short f2bf(float f){
  union { float f; unsigned int i; } x; x.f = f;
  unsigned int r = x.i + 0x7fffu + ((x.i >> 16) & 1u);
  return (unsigned short)(r >> 16);
}

// ---------------- fp32 -> bf16 bulk convert (weights) ----------------
__global__ __launch_bounds__(256) void cvt_f2b(const float* __restrict__ in,
                                               unsigned short* __restrict__ out, int n)
{
  int i = (blockIdx.x * 256 + threadIdx.x) * 4;
  if (i < n) {
    float4 f = *(const float4*)(in + i);
    union { int2 v; unsigned short u[4]; } o;
    o.u[0] = f2bf(f.x); o.u[1] = f2bf(f.y); o.u[2] = f2bf(f.z); o.u[3] = f2bf(f.w);
    *(int2*)(out + i) = o.v;
  }
}

// ---------------- LayerNorm: fp32 in -> bf16 out, one block per row of 1024 ----
// torch variant: unbiased std (ddof=1), eps added to std (not var)
__global__ __launch_bounds__(256) void ln_kernel(const float* __restrict__ in,
    const float* __restrict__ gam, const float* __restrict__ bet,
    unsigned short* __restrict__ out)
{
  const int row = blockIdx.x, t = threadIdx.x;
  const int base = t * 4;
  float4 raw = *(const float4*)(in + (size_t)row * D_MODEL + base);
  float v[4] = { raw.x, raw.y, raw.z, raw.w };
  float s  = v[0] + v[1] + v[2] + v[3];
  float s2 = v[0]*v[0] + v[1]*v[1] + v[2]*v[2] + v[3]*v[3];
  #pragma unroll
  for (int off = 32; off > 0; off >>= 1) {
    s  += __shfl_down(s,  off);
    s2 += __shfl_down(s2, off);
  }
  __shared__ float red[10];
  const int wid = t >> 6, lane = t & 63;
  if (lane == 0) { red[wid] = s; red[4 + wid] = s2; }
  __syncthreads();
  if (t == 0) {
    float ts  = red[0] + red[1] + red[2] + red[3];
    float ts2 = red[4] + red[5] + red[6] + red[7];
    float mean = ts * (1.0f / D_MODEL);
    float var  = (ts2 - (float)D_MODEL * mean * mean) * (1.0f / (D_MODEL - 1));
    var = fmaxf(var, 0.0f);
    red[8] = mean;
    red[9] = 1.0f / (sqrtf(var) + 1e-6f);
  }
  __syncthreads();
  const float mean = red[8], inv = red[9];
  float4 g4 = *(const float4*)(gam + base);
  float4 b4 = *(const float4*)(bet + base);
  union { int2 v; unsigned short u[4]; } o;
  o.u[0] = f2bf(g4.x * (v[0] - mean) * inv + b4.x);
  o.u[1] = f2bf(g4.y * (v[1] - mean) * inv + b4.y);
  o.u[2] = f2bf(g4.z * (v[2] - mean) * inv + b4.z);
  o.u[3] = f2bf(g4.w * (v[3] - mean) * inv + b4.w);
  *(int2*)(out + (size_t)row * D_MODEL + base) = o.v;
}

// ---------------- GEMM: C[m,n] = sum_k A[m,k] * Bw[n,k]  (+ epilogue) ----------
// A bf16 [M,K]; B either bf16 [N,K] (BF16B) or fp32 [N,K] (cvt during staging).
// 128x128 tile, BK=32, 4 waves (2x2), each wave 64x64 via 4x4 mfma_16x16x32_bf16.
// outbT: optional transposed bf16 output at [(b,h),d,s] for the V projection.
template<bool BF16B>
__global__ __launch_bounds__(256) void gemm_bt(
    const unsigned short* __restrict__ A,   // [M,K] bf16
    const void* __restrict__ Bw_,           // [N,K] bf16 or fp32
    int K, int N,
    const float* __restrict__ bias,    // [N] fp32 or null
    int relu,
    const float* __restrict__ residf,  // [M,N] fp32 or null
    unsigned short* __restrict__ outb, // [M,N] bf16 or null
    unsigned short* __restrict__ outbT,// transposed bf16 or null
    float* __restrict__ outf)          // [M,N] fp32 or null
{
  __shared__ short sA[128 * 32];
  __shared__ short sB[128 * 32];
  const int t = threadIdx.x;
  const int tileN = blockIdx.x * 128;
  const int tileM = blockIdx.y * 128;
  const int wid = t >> 6, lane = t & 63;
  const int wM = (wid >> 1) * 64, wN = (wid & 1) * 64;
  const int quad = lane >> 4, lrow = lane & 15;

  f32x4 acc[4][4] = {};

  for (int k0 = 0; k0 < K; k0 += 32) {
    #pragma unroll
    for (int it = 0; it < 2; it++) {
      int seg = it * 256 + t;            // 512 x 8-element segments per tile
      int row = seg >> 2, c8 = (seg & 3) * 8;
      *(int4*)&sA[row * 32 + c8] = *(const int4*)(A + (size_t)(tileM + row) * K + k0 + c8);
      if constexpr (BF16B) {
        const unsigned short* bsrc = (const unsigned short*)Bw_ + (size_t)(tileN + row) * K + k0 + c8;
        *(int4*)&sB[row * 32 + c8] = *(const int4*)bsrc;
      } else {
        const float* bsrc = (const float*)Bw_ + (size_t)(tileN + row) * K + k0 + c8;
        float4 f0 = *(const float4*)bsrc;
        float4 f1 = *(const float4*)(bsrc + 4);
        union { int4 v; unsigned short u[8]; } bb;
        bb.u[0] = f2bf(f0.x); bb.u[1] = f2bf(f0.y); bb.u[2] = f2bf(f0.z); bb.u[3] = f2bf(f0.w);
        bb.u[4] = f2bf(f1.x); bb.u[5] = f2bf(f1.y); bb.u[6] = f2bf(f1.z); bb.u[7] = f2bf(f1.w);
        *(int4*)&sB[row * 32 + c8] = bb.v;
      }
    }
    __syncthreads();
    bf16x8 af[4], bfr[4];
    #pragma unroll
    for (int i = 0; i < 4; i++) {
      af[i]  = *(const bf16x8*)&sA[(wM + i * 16 + lrow) * 32 + quad * 8];
      bfr[i] = *(const bf16x8*)&sB[(wN + i * 16 + lrow) * 32 + quad * 8];
    }
    #pragma unroll
    for (int i = 0; i < 4; i++)
      #pragma unroll
      for (int j = 0; j < 4; j++)
        acc[i][j] = __builtin_amdgcn_mfma_f32_16x16x32_bf16(af[i], bfr[j], acc[i][j], 0, 0, 0);
    __syncthreads();
  }

  #pragma unroll
  for (int i = 0; i < 4; i++) {
    #pragma unroll
    for (int j = 0; j < 4; j++) {
      const int col  = tileN + wN + j * 16 + lrow;
      const int row0 = tileM + wM + i * 16 + quad * 4;
      const float bv = bias ? bias[col] : 0.0f;
      float vals[4];
      #pragma unroll
      for (int r = 0; r < 4; r++) {
        float val = acc[i][j][r] + bv;
        if (relu) val = fmaxf(val, 0.0f);
        if (residf) val += residf[(size_t)(row0 + r) * N + col];
        vals[r] = val;
      }
      if (outbT) {
        // vt[((b*NH + h)*DK + d)*SEQ + s], b=row>>11, s=row&2047, h=col>>6, d=col&63
        union { int2 v; unsigned short u[4]; } pk;
        #pragma unroll
        for (int r = 0; r < 4; r++) pk.u[r] = f2bf(vals[r]);
        size_t tidx = (((size_t)(row0 >> 11) * NH + (col >> 6)) * DK + (col & 63)) * SEQ + (row0 & 2047);
        *(int2*)(outbT + tidx) = pk.v;
      } else {
        #pragma unroll
        for (int r = 0; r < 4; r++) {
          const size_t idx = (size_t)(row0 + r) * N + col;
          if (outf) outf[idx] = vals[r];
          if (outb) outb[idx] = f2bf(vals[r]);
        }
      }
    }
  }
}

// ---------------- MFMA flash attention ----------------
// Block = 4 waves, 64 Q-rows of one (b,h). KV tiles of 64. Online softmax.
// Layouts mirror gemm_bt's verified fragment conventions.
// Og may alias Qg (Q frags register-resident before any write).
#define AQT 64
#define AKT 64
#define LST 72   // LDS row stride (elems): b128 reads <=2-way conflicts
__global__ __launch_bounds__(256) void attn_mfma(
    const unsigned short* __restrict__ Qg,   // [B*S][D_MODEL] bf16
    const unsigned short* __restrict__ Kg,   // [B*S][D_MODEL] bf16
    const unsigned short* __restrict__ Vt,   // [(b*NH+h)*DK + d][SEQ] bf16 (transposed)
    const int* __restrict__ mask,            // [B*S]
    unsigned short* __restrict__ Og)
{
  __shared__ short Ks[AKT * LST];
  __shared__ short Vs[DK * LST];     // V^T tile: row=d, col=kv
  __shared__ short Ps[AQT * LST];
  __shared__ float maddf[AKT];

  const int bid = blockIdx.x;
  const int nqt = SEQ / AQT;          // 32
  const int b  = bid / (NH * nqt);
  const int h  = (bid / nqt) % NH;
  const int q0 = (bid % nqt) * AQT;
  const int t  = threadIdx.x;
  const int wv = t >> 6, lane = t & 63;
  const int quad = lane >> 4, l15 = lane & 15;

  // Q A-frags: m=l15 (q-row within wave's 16), k=quad*8+j; chunks k0=0,32
  bf16x8 qf0, qf1;
  {
    const unsigned short* qrow = Qg + (size_t)(b * SEQ + q0 + wv * 16 + l15) * D_MODEL + h * DK;
    qf0 = *(const bf16x8*)(qrow + quad * 8);
    qf1 = *(const bf16x8*)(qrow + 32 + quad * 8);
  }
  f32x4 oacc[4] = {};                 // dt=0..3, C-layout rows quad*4+r
  float m_run[4], l_run[4];
  #pragma unroll
  for (int r = 0; r < 4; r++) { m_run[r] = -1e30f; l_run[r] = 0.0f; }

  for (int kt = 0; kt < SEQ; kt += AKT) {
    // stage K [kv][dk] and V^T [d][kv]
    #pragma unroll
    for (int it = 0; it < 2; it++) {
      int s = it * 256 + t;
      int row = s >> 3, c8 = (s & 7) * 8;
      *(int4*)&Ks[row * LST + c8] =
        *(const int4*)(Kg + (size_t)(b * SEQ + kt + row) * D_MODEL + h * DK + c8);
      *(int4*)&Vs[row * LST + c8] =
        *(const int4*)(Vt + ((size_t)(b * NH + h) * DK + row) * SEQ + kt + c8);
    }
    if (t < AKT) maddf[t] = mask[b * SEQ + kt + t] ? 0.0f : -1e9f;
    __syncthreads();

    // scores: 4 col-tiles of 16 kv each
    f32x4 sc[4];
    #pragma unroll
    for (int ct = 0; ct < 4; ct++) {
      bf16x8 kb0 = *(const bf16x8*)&Ks[(ct * 16 + l15) * LST + quad * 8];
      bf16x8 kb1 = *(const bf16x8*)&Ks[(ct * 16 + l15) * LST + 32 + quad * 8];
      f32x4 a = {};
      a = __builtin_amdgcn_mfma_f32_16x16x32_bf16(qf0, kb0, a, 0, 0, 0);
      a = __builtin_amdgcn_mfma_f32_16x16x32_bf16(qf1, kb1, a, 0, 0, 0);
      float madd = maddf[ct * 16 + l15];
      #pragma unroll
      for (int r = 0; r < 4; r++) a[r] = a[r] * 0.125f + madd;
      sc[ct] = a;
    }
    // row max over 64 kv: within-lane over ct, then 16-lane shuffle reduce
    float tmax[4];
    #pragma unroll
    for (int r = 0; r < 4; r++)
      tmax[r] = fmaxf(fmaxf(sc[0][r], sc[1][r]), fmaxf(sc[2][r], sc[3][r]));
    #pragma unroll
    for (int off = 1; off < 16; off <<= 1)
      #pragma unroll
      for (int r = 0; r < 4; r++)
        tmax[r] = fmaxf(tmax[r], __shfl_xor(tmax[r], off));
    float alpha[4];
    #pragma unroll
    for (int r = 0; r < 4; r++) {
      float mn = fmaxf(m_run[r], tmax[r]);
      alpha[r] = __expf(m_run[r] - mn);
      m_run[r] = mn;
    }
    // p = exp(s - m), row-sum, write P to LDS (bf16)
    float rs[4] = {0.f, 0.f, 0.f, 0.f};
    #pragma unroll
    for (int ct = 0; ct < 4; ct++)
      #pragma unroll
      for (int r = 0; r < 4; r++) {
        float p = __expf(sc[ct][r] - m_run[r]);
        rs[r] += p;
        Ps[(wv * 16 + quad * 4 + r) * LST + ct * 16 + l15] = (short)f2bf(p);
      }
    #pragma unroll
    for (int off = 1; off < 16; off <<= 1)
      #pragma unroll
      for (int r = 0; r < 4; r++)
        rs[r] += __shfl_xor(rs[r], off);
    #pragma unroll
    for (int r = 0; r < 4; r++) l_run[r] = l_run[r] * alpha[r] + rs[r];
    // rescale O
    #pragma unroll
    for (int dt = 0; dt < 4; dt++)
      #pragma unroll
      for (int r = 0; r < 4; r++) oacc[dt][r] *= alpha[r];
    // PV: A = P (own wave's rows only: no barrier needed), B = V^T rows
    bf16x8 pf0 = *(const bf16x8*)&Ps[(wv * 16 + l15) * LST + quad * 8];
    bf16x8 pf1 = *(const bf16x8*)&Ps[(wv * 16 + l15) * LST + 32 + quad * 8];
    #pragma unroll
    for (int dt = 0; dt < 4; dt++) {
      bf16x8 vb0 = *(const bf16x8*)&Vs[(dt * 16 + l15) * LST + quad * 8];
      bf16x8 vb1 = *(const bf16x8*)&Vs[(dt * 16 + l15) * LST + 32 + quad * 8];
      oacc[dt] = __builtin_amdgcn_mfma_f32_16x16x32_bf16(pf0, vb0, oacc[dt], 0, 0, 0);
      oacc[dt] = __builtin_amdgcn_mfma_f32_16x16x32_bf16(pf1, vb1, oacc[dt], 0, 0, 0);
    }
    __syncthreads();  // protect Ks/Vs before next staging
  }

  float linv[4];
  #pragma unroll
  for (int r = 0; r < 4; r++) linv[r] = 1.0f / l_run[r];
  #pragma unroll
  for (int dt = 0; dt < 4; dt++)
    #pragma unroll
    for (int r = 0; r < 4; r++)
      Og[(size_t)(b * SEQ + q0 + wv * 16 + quad * 4 + r) * D_MODEL + h * DK + dt * 16 + l15] =
        f2bf(oacc[dt][r] * linv[r]);
}

// ---------------- launch ----------------
// fp32 I/O. Internal bf16. Workspace (bf16-weight path, 72MB):
//   [ 0,16) q (-> attn out -> ln2)   [16,32) k (-> FFN hidden chunk)
//   [32,48) vt (transposed V)        [48,72) bf16 weights
// ln1 (bf16) in d_out's first 16MB; x1 (fp32) = d_out.
// Fallback (ws < 80MB): fp32-B GEMMs, 48MB high-water.
extern "C" void kernel_launch(void* const* d_in, const int* in_sizes, int n_in,
                              void* d_out, int out_size, void* d_ws, size_t ws_size,
                              hipStream_t stream)
{
  (void)in_sizes; (void)n_in; (void)out_size;
  const float* x   = (const float*)d_in[0];
  const int*   msk = (const int*)d_in[1];
  const float* w_q = (const float*)d_in[2];
  const float* w_k = (const float*)d_in[3];
  const float* w_v = (const float*)d_in[4];
  const float* w_o = (const float*)d_in[5];
  const float* w1  = (const float*)d_in[6];
  const float* b1  = (const float*)d_in[7];
  const float* w2  = (const float*)d_in[8];
  const float* b2  = (const float*)d_in[9];
  const float* g1  = (const float*)d_in[10];
  const float* be1 = (const float*)d_in[11];
  const float* g2  = (const float*)d_in[12];
  const float* be2 = (const float*)d_in[13];
  float* outf = (float*)d_out;

  char* ws = (char*)d_ws;
  const size_t MB = 1024 * 1024;
  const bool wbf16 = (ws_size >= 80 * MB);   // call-invariant -> graph-safe

  unsigned short* q_b  = (unsigned short*)(ws + 0);        // 16MB
  unsigned short* k_b  = (unsigned short*)(ws + 16 * MB);  // 16MB
  unsigned short* vt_b = (unsigned short*)(ws + 32 * MB);  // 16MB
  unsigned short* ln1b = (unsigned short*)d_out;           // first 16MB of d_out
  unsigned short* ln2b = q_b;
  unsigned short* hffc = k_b;
  unsigned short* wq16 = (unsigned short*)(ws + 48 * MB);
  unsigned short* wk16 = (unsigned short*)(ws + 50 * MB);
  unsigned short* wv16 = (unsigned short*)(ws + 52 * MB);
  unsigned short* wo16 = (unsigned short*)(ws + 54 * MB);
  unsigned short* w116 = (unsigned short*)(ws + 56 * MB);
  unsigned short* w216 = (unsigned short*)(ws + 64 * MB);

  dim3 blk(256);
  dim3 gN1024(D_MODEL / 128, NROWS / 128);  // (8, 64)

  if (wbf16) {
    const int nw = D_MODEL * D_MODEL;       // 1M
    const int nf = DFF * D_MODEL;           // 4M
    cvt_f2b<<<nw / 1024, blk, 0, stream>>>(w_q, wq16, nw);
    cvt_f2b<<<nw / 1024, blk, 0, stream>>>(w_k, wk16, nw);
    cvt_f2b<<<nw / 1024, blk, 0, stream>>>(w_v, wv16, nw);
    cvt_f2b<<<nw / 1024, blk, 0, stream>>>(w_o, wo16, nw);
    cvt_f2b<<<nf / 1024, blk, 0, stream>>>(w1, w116, nf);
    cvt_f2b<<<nf / 1024, blk, 0, stream>>>(w2, w216, nf);
  }

  // LN1: x -> ln1b (bf16, in d_out)
  ln_kernel<<<NROWS, blk, 0, stream>>>(x, g1, be1, ln1b);

  // Q, K projections; V projection writes TRANSPOSED vt
  if (wbf16) {
    gemm_bt<true><<<gN1024, blk, 0, stream>>>(ln1b, wq16, D_MODEL, D_MODEL, nullptr, 0, nullptr, q_b, nullptr, nullptr);
    gemm_bt<true><<<gN1024, blk, 0, stream>>>(ln1b, wk16, D_MODEL, D_MODEL, nullptr, 0, nullptr, k_b, nullptr, nullptr);
    gemm_bt<true><<<gN1024, blk, 0, stream>>>(ln1b, wv16, D_MODEL, D_MODEL, nullptr, 0, nullptr, nullptr, vt_b, nullptr);
  } else {
    gemm_bt<false><<<gN1024, blk, 0, stream>>>(ln1b, w_q, D_MODEL, D_MODEL, nullptr, 0, nullptr, q_b, nullptr, nullptr);
    gemm_bt<false><<<gN1024, blk, 0, stream>>>(ln1b, w_k, D_MODEL, D_MODEL, nullptr, 0, nullptr, k_b, nullptr, nullptr);
    gemm_bt<false><<<gN1024, blk, 0, stream>>>(ln1b, w_v, D_MODEL, D_MODEL, nullptr, 0, nullptr, nullptr, vt_b, nullptr);
  }

  // attention (MFMA, output in-place over q)
  attn_mfma<<<BATCH * NH * (SEQ / AQT), blk, 0, stream>>>(q_b, k_b, vt_b, msk, q_b);

  // o-proj + residual(x) -> x1 = d_out (fp32)
  if (wbf16)
    gemm_bt<true><<<gN1024, blk, 0, stream>>>(q_b, wo16, D_MODEL, D_MODEL, nullptr, 0, x, nullptr, nullptr, outf);
  else
    gemm_bt<false><<<gN1024, blk, 0, stream>>>(q_b, w_o, D_MODEL, D_MODEL, nullptr, 0, x, nullptr, nullptr, outf);

  // LN2: x1 -> ln2b (bf16, reuses q region)
  ln_kernel<<<NROWS, blk, 0, stream>>>(outf, g2, be2, ln2b);

  // FFN, M-chunked (hidden chunk reuses k region)
  for (int c = 0; c < NCHUNK; c++) {
    const size_t ro = (size_t)c * CHUNK;
    dim3 g1c(DFF / 128,     CHUNK / 128);   // (32, 16)
    dim3 g2c(D_MODEL / 128, CHUNK / 128);   // (8, 16)
    if (wbf16) {
      gemm_bt<true><<<g1c, blk, 0, stream>>>(ln2b + ro * D_MODEL, w116, D_MODEL, DFF, b1, 1, nullptr, hffc, nullptr, nullptr);
      gemm_bt<true><<<g2c, blk, 0, stream>>>(hffc, w216, DFF, D_MODEL, b2, 0,
                                             outf + ro * D_MODEL, nullptr, nullptr, outf + ro * D_MODEL);
    } else {
      gemm_bt<false><<<g1c, blk, 0, stream>>>(ln2b + ro * D_MODEL, w1, D_MODEL, DFF, b1, 1, nullptr, hffc, nullptr, nullptr);
      gemm_bt<false><<<g2c, blk, 0, stream>>>(hffc, w2, DFF, D_MODEL, b2, 0,
                                              outf + ro * D_MODEL, nullptr, nullptr, outf + ro * D_MODEL);
    }
  }
}

// Round 6
// 1101.739 us; speedup vs baseline: 2.6616x; 1.0090x over previous
//
#include <hip/hip_runtime.h>

#define D_MODEL 1024
#define NH 16
#define DK 64
#define DFF 4096
#define SEQ 2048
#define BATCH 4
#define NROWS (BATCH*SEQ)   // 8192
#define CHUNK 2048          // FFN row-chunk
#define NCHUNK (NROWS/CHUNK)

typedef short bf16x8 __attribute__((ext_vector_type(8)));
typedef float f32x4 __attribute__((ext_vector_type(4)));

__device__ __forceinline__ float bf2f(unsigned short u){
  union { float f; unsigned int i; } x; x.i = ((unsigned int)u) << 16; return x.f;
}
__device__ __forceinline__ unsigned short f2bf(float f){
  union { float f; unsigned int i; } x; x.f = f;
  unsigned int r = x.i + 0x7fffu + ((x.i >> 16) & 1u);
  return (unsigned short)(r >> 16);
}

// async global->LDS, 16B per lane (m97 pattern; LDS dest = wave base + lane*16)
__device__ __forceinline__ void gl_lds16(const void* g, void* l) {
  __builtin_amdgcn_global_load_lds((const __attribute__((address_space(1))) void*)g,
                                   (__attribute__((address_space(3))) void*)l, 16, 0, 0);
}

// ---------------- fp32 -> bf16 bulk convert (weights) ----------------
__global__ __launch_bounds__(256) void cvt_f2b(const float* __restrict__ in,
                                               unsigned short* __restrict__ out, int n)
{
  int i = (blockIdx.x * 256 + threadIdx.x) * 4;
  if (i < n) {
    float4 f = *(const float4*)(in + i);
    union { int2 v; unsigned short u[4]; } o;
    o.u[0] = f2bf(f.x); o.u[1] = f2bf(f.y); o.u[2] = f2bf(f.z); o.u[3] = f2bf(f.w);
    *(int2*)(out + i) = o.v;
  }
}

// ---------------- LayerNorm: fp32 in -> bf16 out, one block per row of 1024 ----
// torch variant: unbiased std (ddof=1), eps added to std (not var)
__global__ __launch_bounds__(256) void ln_kernel(const float* __restrict__ in,
    const float* __restrict__ gam, const float* __restrict__ bet,
    unsigned short* __restrict__ out)
{
  const int row = blockIdx.x, t = threadIdx.x;
  const int base = t * 4;
  float4 raw = *(const float4*)(in + (size_t)row * D_MODEL + base);
  float v[4] = { raw.x, raw.y, raw.z, raw.w };
  float s  = v[0] + v[1] + v[2] + v[3];
  float s2 = v[0]*v[0] + v[1]*v[1] + v[2]*v[2] + v[3]*v[3];
  #pragma unroll
  for (int off = 32; off > 0; off >>= 1) {
    s  += __shfl_down(s,  off);
    s2 += __shfl_down(s2, off);
  }
  __shared__ float red[10];
  const int wid = t >> 6, lane = t & 63;
  if (lane == 0) { red[wid] = s; red[4 + wid] = s2; }
  __syncthreads();
  if (t == 0) {
    float ts  = red[0] + red[1] + red[2] + red[3];
    float ts2 = red[4] + red[5] + red[6] + red[7];
    float mean = ts * (1.0f / D_MODEL);
    float var  = (ts2 - (float)D_MODEL * mean * mean) * (1.0f / (D_MODEL - 1));
    var = fmaxf(var, 0.0f);
    red[8] = mean;
    red[9] = 1.0f / (sqrtf(var) + 1e-6f);
  }
  __syncthreads();
  const float mean = red[8], inv = red[9];
  float4 g4 = *(const float4*)(gam + base);
  float4 b4 = *(const float4*)(bet + base);
  union { int2 v; unsigned short u[4]; } o;
  o.u[0] = f2bf(g4.x * (v[0] - mean) * inv + b4.x);
  o.u[1] = f2bf(g4.y * (v[1] - mean) * inv + b4.y);
  o.u[2] = f2bf(g4.z * (v[2] - mean) * inv + b4.z);
  o.u[3] = f2bf(g4.w * (v[3] - mean) * inv + b4.w);
  *(int2*)(out + (size_t)row * D_MODEL + base) = o.v;
}

// ---------------- GEMM: C[m,n] = sum_k A[m,k] * Bw[n,k]  (+ epilogue) ----------
// A bf16 [M,K]; B either bf16 [N,K] (BF16B, global_load_lds staging) or fp32 (cvt).
// 128x128 tile, BK=32, 4 waves (2x2), each wave 64x64 via 4x4 mfma_16x16x32_bf16.
// outbT: optional transposed bf16 output at [(b,h),d,s] for the V projection.
template<bool BF16B>
__global__ __launch_bounds__(256) void gemm_bt(
    const unsigned short* __restrict__ A,   // [M,K] bf16
    const void* __restrict__ Bw_,           // [N,K] bf16 or fp32
    int K, int N,
    const float* __restrict__ bias,    // [N] fp32 or null
    int relu,
    const float* __restrict__ residf,  // [M,N] fp32 or null
    unsigned short* __restrict__ outb, // [M,N] bf16 or null
    unsigned short* __restrict__ outbT,// transposed bf16 or null
    float* __restrict__ outf)          // [M,N] fp32 or null
{
  __shared__ __attribute__((aligned(16))) short sA[128 * 32];
  __shared__ __attribute__((aligned(16))) short sB[128 * 32];
  const int t = threadIdx.x;
  const int tileN = blockIdx.x * 128;
  const int tileM = blockIdx.y * 128;
  const int wid = t >> 6, lane = t & 63;
  const int wM = (wid >> 1) * 64, wN = (wid & 1) * 64;
  const int quad = lane >> 4, lrow = lane & 15;

  f32x4 acc[4][4] = {};

  for (int k0 = 0; k0 < K; k0 += 32) {
    #pragma unroll
    for (int it = 0; it < 2; it++) {
      int seg = it * 256 + t;            // 512 x 8-element (16B) segments per tile
      int row = seg >> 2, c8 = (seg & 3) * 8;
      if constexpr (BF16B) {
        // async DMA: LDS byte offset = seg*16 == wave base + lane*16 (unpadded)
        gl_lds16(A + (size_t)(tileM + row) * K + k0 + c8, &sA[seg * 8]);
        gl_lds16((const unsigned short*)Bw_ + (size_t)(tileN + row) * K + k0 + c8, &sB[seg * 8]);
      } else {
        *(int4*)&sA[row * 32 + c8] = *(const int4*)(A + (size_t)(tileM + row) * K + k0 + c8);
        const float* bsrc = (const float*)Bw_ + (size_t)(tileN + row) * K + k0 + c8;
        float4 f0 = *(const float4*)bsrc;
        float4 f1 = *(const float4*)(bsrc + 4);
        union { int4 v; unsigned short u[8]; } bb;
        bb.u[0] = f2bf(f0.x); bb.u[1] = f2bf(f0.y); bb.u[2] = f2bf(f0.z); bb.u[3] = f2bf(f0.w);
        bb.u[4] = f2bf(f1.x); bb.u[5] = f2bf(f1.y); bb.u[6] = f2bf(f1.z); bb.u[7] = f2bf(f1.w);
        *(int4*)&sB[row * 32 + c8] = bb.v;
      }
    }
    __syncthreads();
    bf16x8 af[4], bfr[4];
    #pragma unroll
    for (int i = 0; i < 4; i++) {
      af[i]  = *(const bf16x8*)&sA[(wM + i * 16 + lrow) * 32 + quad * 8];
      bfr[i] = *(const bf16x8*)&sB[(wN + i * 16 + lrow) * 32 + quad * 8];
    }
    #pragma unroll
    for (int i = 0; i < 4; i++)
      #pragma unroll
      for (int j = 0; j < 4; j++)
        acc[i][j] = __builtin_amdgcn_mfma_f32_16x16x32_bf16(af[i], bfr[j], acc[i][j], 0, 0, 0);
    __syncthreads();
  }

  #pragma unroll
  for (int i = 0; i < 4; i++) {
    #pragma unroll
    for (int j = 0; j < 4; j++) {
      const int col  = tileN + wN + j * 16 + lrow;
      const int row0 = tileM + wM + i * 16 + quad * 4;
      const float bv = bias ? bias[col] : 0.0f;
      float vals[4];
      #pragma unroll
      for (int r = 0; r < 4; r++) {
        float val = acc[i][j][r] + bv;
        if (relu) val = fmaxf(val, 0.0f);
        if (residf) val += residf[(size_t)(row0 + r) * N + col];
        vals[r] = val;
      }
      if (outbT) {
        // vt[((b*NH + h)*DK + d)*SEQ + s], b=row>>11, s=row&2047, h=col>>6, d=col&63
        union { int2 v; unsigned short u[4]; } pk;
        #pragma unroll
        for (int r = 0; r < 4; r++) pk.u[r] = f2bf(vals[r]);
        size_t tidx = (((size_t)(row0 >> 11) * NH + (col >> 6)) * DK + (col & 63)) * SEQ + (row0 & 2047);
        *(int2*)(outbT + tidx) = pk.v;
      } else {
        #pragma unroll
        for (int r = 0; r < 4; r++) {
          const size_t idx = (size_t)(row0 + r) * N + col;
          if (outf) outf[idx] = vals[r];
          if (outb) outb[idx] = f2bf(vals[r]);
        }
      }
    }
  }
}

// ---------------- MFMA flash attention ----------------
// Block = 4 waves, 64 Q-rows of one (b,h). KV tiles of 64. Online softmax.
// Og may alias Qg (Q frags register-resident before any write).
#define AQT 64
#define AKT 64
#define LST 72   // LDS row stride (elems): b128 reads <=2-way conflicts
__global__ __launch_bounds__(256) void attn_mfma(
    const unsigned short* __restrict__ Qg,   // [B*S][D_MODEL] bf16
    const unsigned short* __restrict__ Kg,   // [B*S][D_MODEL] bf16
    const unsigned short* __restrict__ Vt,   // [(b*NH+h)*DK + d][SEQ] bf16 (transposed)
    const int* __restrict__ mask,            // [B*S]
    unsigned short* __restrict__ Og)
{
  __shared__ short Ks[AKT * LST];
  __shared__ short Vs[DK * LST];     // V^T tile: row=d, col=kv
  __shared__ short Ps[AQT * LST];
  __shared__ float maddf[AKT];

  const int bid = blockIdx.x;
  const int nqt = SEQ / AQT;          // 32
  const int b  = bid / (NH * nqt);
  const int h  = (bid / nqt) % NH;
  const int q0 = (bid % nqt) * AQT;
  const int t  = threadIdx.x;
  const int wv = t >> 6, lane = t & 63;
  const int quad = lane >> 4, l15 = lane & 15;

  // Q A-frags: m=l15, k=quad*8+j; chunks k0=0,32
  bf16x8 qf0, qf1;
  {
    const unsigned short* qrow = Qg + (size_t)(b * SEQ + q0 + wv * 16 + l15) * D_MODEL + h * DK;
    qf0 = *(const bf16x8*)(qrow + quad * 8);
    qf1 = *(const bf16x8*)(qrow + 32 + quad * 8);
  }
  f32x4 oacc[4] = {};
  float m_run[4], l_run[4];
  #pragma unroll
  for (int r = 0; r < 4; r++) { m_run[r] = -1e30f; l_run[r] = 0.0f; }

  for (int kt = 0; kt < SEQ; kt += AKT) {
    #pragma unroll
    for (int it = 0; it < 2; it++) {
      int s = it * 256 + t;
      int row = s >> 3, c8 = (s & 7) * 8;
      *(int4*)&Ks[row * LST + c8] =
        *(const int4*)(Kg + (size_t)(b * SEQ + kt + row) * D_MODEL + h * DK + c8);
      *(int4*)&Vs[row * LST + c8] =
        *(const int4*)(Vt + ((size_t)(b * NH + h) * DK + row) * SEQ + kt + c8);
    }
    if (t < AKT) maddf[t] = mask[b * SEQ + kt + t] ? 0.0f : -1e9f;
    __syncthreads();

    f32x4 sc[4];
    #pragma unroll
    for (int ct = 0; ct < 4; ct++) {
      bf16x8 kb0 = *(const bf16x8*)&Ks[(ct * 16 + l15) * LST + quad * 8];
      bf16x8 kb1 = *(const bf16x8*)&Ks[(ct * 16 + l15) * LST + 32 + quad * 8];
      f32x4 a = {};
      a = __builtin_amdgcn_mfma_f32_16x16x32_bf16(qf0, kb0, a, 0, 0, 0);
      a = __builtin_amdgcn_mfma_f32_16x16x32_bf16(qf1, kb1, a, 0, 0, 0);
      float madd = maddf[ct * 16 + l15];
      #pragma unroll
      for (int r = 0; r < 4; r++) a[r] = a[r] * 0.125f + madd;
      sc[ct] = a;
    }
    float tmax[4];
    #pragma unroll
    for (int r = 0; r < 4; r++)
      tmax[r] = fmaxf(fmaxf(sc[0][r], sc[1][r]), fmaxf(sc[2][r], sc[3][r]));
    #pragma unroll
    for (int off = 1; off < 16; off <<= 1)
      #pragma unroll
      for (int r = 0; r < 4; r++)
        tmax[r] = fmaxf(tmax[r], __shfl_xor(tmax[r], off));
    float alpha[4];
    #pragma unroll
    for (int r = 0; r < 4; r++) {
      float mn = fmaxf(m_run[r], tmax[r]);
      alpha[r] = __expf(m_run[r] - mn);
      m_run[r] = mn;
    }
    float rs[4] = {0.f, 0.f, 0.f, 0.f};
    #pragma unroll
    for (int ct = 0; ct < 4; ct++)
      #pragma unroll
      for (int r = 0; r < 4; r++) {
        float p = __expf(sc[ct][r] - m_run[r]);
        rs[r] += p;
        Ps[(wv * 16 + quad * 4 + r) * LST + ct * 16 + l15] = (short)f2bf(p);
      }
    #pragma unroll
    for (int off = 1; off < 16; off <<= 1)
      #pragma unroll
      for (int r = 0; r < 4; r++)
        rs[r] += __shfl_xor(rs[r], off);
    #pragma unroll
    for (int r = 0; r < 4; r++) l_run[r] = l_run[r] * alpha[r] + rs[r];
    #pragma unroll
    for (int dt = 0; dt < 4; dt++)
      #pragma unroll
      for (int r = 0; r < 4; r++) oacc[dt][r] *= alpha[r];
    bf16x8 pf0 = *(const bf16x8*)&Ps[(wv * 16 + l15) * LST + quad * 8];
    bf16x8 pf1 = *(const bf16x8*)&Ps[(wv * 16 + l15) * LST + 32 + quad * 8];
    #pragma unroll
    for (int dt = 0; dt < 4; dt++) {
      bf16x8 vb0 = *(const bf16x8*)&Vs[(dt * 16 + l15) * LST + quad * 8];
      bf16x8 vb1 = *(const bf16x8*)&Vs[(dt * 16 + l15) * LST + 32 + quad * 8];
      oacc[dt] = __builtin_amdgcn_mfma_f32_16x16x32_bf16(pf0, vb0, oacc[dt], 0, 0, 0);
      oacc[dt] = __builtin_amdgcn_mfma_f32_16x16x32_bf16(pf1, vb1, oacc[dt], 0, 0, 0);
    }
    __syncthreads();
  }

  float linv[4];
  #pragma unroll
  for (int r = 0; r < 4; r++) linv[r] = 1.0f / l_run[r];
  #pragma unroll
  for (int dt = 0; dt < 4; dt++)
    #pragma unroll
    for (int r = 0; r < 4; r++)
      Og[(size_t)(b * SEQ + q0 + wv * 16 + quad * 4 + r) * D_MODEL + h * DK + dt * 16 + l15] =
        f2bf(oacc[dt][r] * linv[r]);
}

// ---------------- launch ----------------
// fp32 I/O. Internal bf16. Workspace (bf16-weight path, 72MB):
//   [ 0,16) q (-> attn out -> ln2)   [16,32) k (-> FFN hidden chunk)
//   [32,48) vt (transposed V)        [48,72) bf16 weights
// ln1 (bf16) in d_out's first 16MB; x1 (fp32) = d_out.
// Fallback (ws < 80MB): fp32-B GEMMs, 48MB high-water.
extern "C" void kernel_launch(void* const* d_in, const int* in_sizes, int n_in,
                              void* d_out, int out_size, void* d_ws, size_t ws_size,
                              hipStream_t stream)
{
  (void)in_sizes; (void)n_in; (void)out_size;
  const float* x   = (const float*)d_in[0];
  const int*   msk = (const int*)d_in[1];
  const float* w_q = (const float*)d_in[2];
  const float* w_k = (const float*)d_in[3];
  const float* w_v = (const float*)d_in[4];
  const float* w_o = (const float*)d_in[5];
  const float* w1  = (const float*)d_in[6];
  const float* b1  = (const float*)d_in[7];
  const float* w2  = (const float*)d_in[8];
  const float* b2  = (const float*)d_in[9];
  const float* g1  = (const float*)d_in[10];
  const float* be1 = (const float*)d_in[11];
  const float* g2  = (const float*)d_in[12];
  const float* be2 = (const float*)d_in[13];
  float* outf = (float*)d_out;

  char* ws = (char*)d_ws;
  const size_t MB = 1024 * 1024;
  const bool wbf16 = (ws_size >= 80 * MB);   // call-invariant -> graph-safe

  unsigned short* q_b  = (unsigned short*)(ws + 0);        // 16MB
  unsigned short* k_b  = (unsigned short*)(ws + 16 * MB);  // 16MB
  unsigned short* vt_b = (unsigned short*)(ws + 32 * MB);  // 16MB
  unsigned short* ln1b = (unsigned short*)d_out;           // first 16MB of d_out
  unsigned short* ln2b = q_b;
  unsigned short* hffc = k_b;
  unsigned short* wq16 = (unsigned short*)(ws + 48 * MB);
  unsigned short* wk16 = (unsigned short*)(ws + 50 * MB);
  unsigned short* wv16 = (unsigned short*)(ws + 52 * MB);
  unsigned short* wo16 = (unsigned short*)(ws + 54 * MB);
  unsigned short* w116 = (unsigned short*)(ws + 56 * MB);
  unsigned short* w216 = (unsigned short*)(ws + 64 * MB);

  dim3 blk(256);
  dim3 gN1024(D_MODEL / 128, NROWS / 128);  // (8, 64)

  if (wbf16) {
    const int nw = D_MODEL * D_MODEL;       // 1M
    const int nf = DFF * D_MODEL;           // 4M
    cvt_f2b<<<nw / 1024, blk, 0, stream>>>(w_q, wq16, nw);
    cvt_f2b<<<nw / 1024, blk, 0, stream>>>(w_k, wk16, nw);
    cvt_f2b<<<nw / 1024, blk, 0, stream>>>(w_v, wv16, nw);
    cvt_f2b<<<nw / 1024, blk, 0, stream>>>(w_o, wo16, nw);
    cvt_f2b<<<nf / 1024, blk, 0, stream>>>(w1, w116, nf);
    cvt_f2b<<<nf / 1024, blk, 0, stream>>>(w2, w216, nf);
  }

  // LN1: x -> ln1b (bf16, in d_out)
  ln_kernel<<<NROWS, blk, 0, stream>>>(x, g1, be1, ln1b);

  // Q, K projections; V projection writes TRANSPOSED vt
  if (wbf16) {
    gemm_bt<true><<<gN1024, blk, 0, stream>>>(ln1b, wq16, D_MODEL, D_MODEL, nullptr, 0, nullptr, q_b, nullptr, nullptr);
    gemm_bt<true><<<gN1024, blk, 0, stream>>>(ln1b, wk16, D_MODEL, D_MODEL, nullptr, 0, nullptr, k_b, nullptr, nullptr);
    gemm_bt<true><<<gN1024, blk, 0, stream>>>(ln1b, wv16, D_MODEL, D_MODEL, nullptr, 0, nullptr, nullptr, vt_b, nullptr);
  } else {
    gemm_bt<false><<<gN1024, blk, 0, stream>>>(ln1b, w_q, D_MODEL, D_MODEL, nullptr, 0, nullptr, q_b, nullptr, nullptr);
    gemm_bt<false><<<gN1024, blk, 0, stream>>>(ln1b, w_k, D_MODEL, D_MODEL, nullptr, 0, nullptr, k_b, nullptr, nullptr);
    gemm_bt<false><<<gN1024, blk, 0, stream>>>(ln1b, w_v, D_MODEL, D_MODEL, nullptr, 0, nullptr, nullptr, vt_b, nullptr);
  }

  // attention (MFMA, output in-place over q)
  attn_mfma<<<BATCH * NH * (SEQ / AQT), blk, 0, stream>>>(q_b, k_b, vt_b, msk, q_b);

  // o-proj + residual(x) -> x1 = d_out (fp32)
  if (wbf16)
    gemm_bt<true><<<gN1024, blk, 0, stream>>>(q_b, wo16, D_MODEL, D_MODEL, nullptr, 0, x, nullptr, nullptr, outf);
  else
    gemm_bt<false><<<gN1024, blk, 0, stream>>>(q_b, w_o, D_MODEL, D_MODEL, nullptr, 0, x, nullptr, nullptr, outf);

  // LN2: x1 -> ln2b (bf16, reuses q region)
  ln_kernel<<<NROWS, blk, 0, stream>>>(outf, g2, be2, ln2b);

  // FFN, M-chunked (hidden chunk reuses k region)
  for (int c = 0; c < NCHUNK; c++) {
    const size_t ro = (size_t)c * CHUNK;
    dim3 g1c(DFF / 128,     CHUNK / 128);   // (32, 16)
    dim3 g2c(D_MODEL / 128, CHUNK / 128);   // (8, 16)
    if (wbf16) {
      gemm_bt<true><<<g1c, blk, 0, stream>>>(ln2b + ro * D_MODEL, w116, D_MODEL, DFF, b1, 1, nullptr, hffc, nullptr, nullptr);
      gemm_bt<true><<<g2c, blk, 0, stream>>>(hffc, w216, DFF, D_MODEL, b2, 0,
                                             outf + ro * D_MODEL, nullptr, nullptr, outf + ro * D_MODEL);
    } else {
      gemm_bt<false><<<g1c, blk, 0, stream>>>(ln2b + ro * D_MODEL, w1, D_MODEL, DFF, b1, 1, nullptr, hffc, nullptr, nullptr);
      gemm_bt<false><<<g2c, blk, 0, stream>>>(hffc, w2, DFF, D_MODEL, b2, 0,
                                              outf + ro * D_MODEL, nullptr, nullptr, outf + ro * D_MODEL);
    }
  }
}

// Round 7
// 1072.484 us; speedup vs baseline: 2.7343x; 1.0273x over previous
//
#include <hip/hip_runtime.h>

#define D_MODEL 1024
#define NH 16
#define DK 64
#define DFF 4096
#define SEQ 2048
#define BATCH 4
#define NROWS (BATCH*SEQ)   // 8192
#define CHUNK 2048          // FFN row-chunk (16MB bf16 hidden fits dead k region)
#define NCHUNK (NROWS/CHUNK)

typedef short bf16x8 __attribute__((ext_vector_type(8)));
typedef float f32x4 __attribute__((ext_vector_type(4)));

__device__ __forceinline__ float bf2f(unsigned short u){
  union { float f; unsigned int i; } x; x.i = ((unsigned int)u) << 16; return x.f;
}
__device__ __forceinline__ unsigned short f2bf(float f){
  union { float f; unsigned int i; } x; x.f = f;
  unsigned int r = x.i + 0x7fffu + ((x.i >> 16) & 1u);
  return (unsigned short)(r >> 16);
}

// async global->LDS, 16B per lane (m97 pattern; LDS dest = wave base + lane*16)
__device__ __forceinline__ void gl_lds16(const void* g, void* l) {
  __builtin_amdgcn_global_load_lds((const __attribute__((address_space(1))) void*)g,
                                   (__attribute__((address_space(3))) void*)l, 16, 0, 0);
}

// ---------------- fp32 -> bf16 bulk convert (weights) ----------------
__global__ __launch_bounds__(256) void cvt_f2b(const float* __restrict__ in,
                                               unsigned short* __restrict__ out, int n)
{
  int i = (blockIdx.x * 256 + threadIdx.x) * 4;
  if (i < n) {
    float4 f = *(const float4*)(in + i);
    union { int2 v; unsigned short u[4]; } o;
    o.u[0] = f2bf(f.x); o.u[1] = f2bf(f.y); o.u[2] = f2bf(f.z); o.u[3] = f2bf(f.w);
    *(int2*)(out + i) = o.v;
  }
}

// ---------------- LayerNorm: fp32 in -> bf16 out, one block per row of 1024 ----
// torch variant: unbiased std (ddof=1), eps added to std (not var)
__global__ __launch_bounds__(256) void ln_kernel(const float* __restrict__ in,
    const float* __restrict__ gam, const float* __restrict__ bet,
    unsigned short* __restrict__ out)
{
  const int row = blockIdx.x, t = threadIdx.x;
  const int base = t * 4;
  float4 raw = *(const float4*)(in + (size_t)row * D_MODEL + base);
  float v[4] = { raw.x, raw.y, raw.z, raw.w };
  float s  = v[0] + v[1] + v[2] + v[3];
  float s2 = v[0]*v[0] + v[1]*v[1] + v[2]*v[2] + v[3]*v[3];
  #pragma unroll
  for (int off = 32; off > 0; off >>= 1) {
    s  += __shfl_down(s,  off);
    s2 += __shfl_down(s2, off);
  }
  __shared__ float red[10];
  const int wid = t >> 6, lane = t & 63;
  if (lane == 0) { red[wid] = s; red[4 + wid] = s2; }
  __syncthreads();
  if (t == 0) {
    float ts  = red[0] + red[1] + red[2] + red[3];
    float ts2 = red[4] + red[5] + red[6] + red[7];
    float mean = ts * (1.0f / D_MODEL);
    float var  = (ts2 - (float)D_MODEL * mean * mean) * (1.0f / (D_MODEL - 1));
    var = fmaxf(var, 0.0f);
    red[8] = mean;
    red[9] = 1.0f / (sqrtf(var) + 1e-6f);
  }
  __syncthreads();
  const float mean = red[8], inv = red[9];
  float4 g4 = *(const float4*)(gam + base);
  float4 b4 = *(const float4*)(bet + base);
  union { int2 v; unsigned short u[4]; } o;
  o.u[0] = f2bf(g4.x * (v[0] - mean) * inv + b4.x);
  o.u[1] = f2bf(g4.y * (v[1] - mean) * inv + b4.y);
  o.u[2] = f2bf(g4.z * (v[2] - mean) * inv + b4.z);
  o.u[3] = f2bf(g4.w * (v[3] - mean) * inv + b4.w);
  *(int2*)(out + (size_t)row * D_MODEL + base) = o.v;
}

// ---------------- GEMM: C[m,n] = sum_k A[m,k] * Bw[n,k]  (+ epilogue) ----------
// All-bf16 operands; global_load_lds width-16 staging (m97 pattern).
// 128x128 tile, BK=32, 4 waves (2x2), each wave 64x64 via 4x4 mfma_16x16x32_bf16.
// QKV mode (outq!=null): N=3072 fused; col block 0->q, 1->k, 2->vt (transposed).
__global__ __launch_bounds__(256) void gemm_bt(
    const unsigned short* __restrict__ A,   // [M,K] bf16
    const unsigned short* __restrict__ Bw,  // [N,K] bf16
    int K, int N,
    const float* __restrict__ bias,    // [N] fp32 or null
    int relu,
    const float* __restrict__ residf,  // [M,N] fp32 or null
    unsigned short* __restrict__ outb, // [M,N] bf16 or null
    float* __restrict__ outf,          // [M,N] fp32 or null
    unsigned short* __restrict__ outq, // fused-QKV q  [M,1024] or null
    unsigned short* __restrict__ outk, //           k  [M,1024]
    unsigned short* __restrict__ outvt)//           v^T [(b,h),d,s]
{
  __shared__ __attribute__((aligned(16))) short sA[128 * 32];
  __shared__ __attribute__((aligned(16))) short sB[128 * 32];
  const int t = threadIdx.x;
  const int tileN = blockIdx.x * 128;
  const int tileM = blockIdx.y * 128;
  const int wid = t >> 6, lane = t & 63;
  const int wM = (wid >> 1) * 64, wN = (wid & 1) * 64;
  const int quad = lane >> 4, lrow = lane & 15;

  f32x4 acc[4][4] = {};

  for (int k0 = 0; k0 < K; k0 += 32) {
    #pragma unroll
    for (int it = 0; it < 2; it++) {
      int seg = it * 256 + t;            // 512 x 16B segments per 8KB tile
      int row = seg >> 2, c8 = (seg & 3) * 8;
      gl_lds16(A  + (size_t)(tileM + row) * K + k0 + c8, &sA[seg * 8]);
      gl_lds16(Bw + (size_t)(tileN + row) * K + k0 + c8, &sB[seg * 8]);
    }
    __syncthreads();
    bf16x8 af[4], bfr[4];
    #pragma unroll
    for (int i = 0; i < 4; i++) {
      af[i]  = *(const bf16x8*)&sA[(wM + i * 16 + lrow) * 32 + quad * 8];
      bfr[i] = *(const bf16x8*)&sB[(wN + i * 16 + lrow) * 32 + quad * 8];
    }
    #pragma unroll
    for (int i = 0; i < 4; i++)
      #pragma unroll
      for (int j = 0; j < 4; j++)
        acc[i][j] = __builtin_amdgcn_mfma_f32_16x16x32_bf16(af[i], bfr[j], acc[i][j], 0, 0, 0);
    __syncthreads();
  }

  // fused-QKV epilogue target for this block (tileN is 128-aligned; one cat/block)
  unsigned short* qk_out = nullptr;
  int qkv_cat = 0;
  if (outq) {
    qkv_cat = tileN >> 10;                 // 0=q 1=k 2=v
    qk_out = (qkv_cat == 0) ? outq : outk;
  }

  #pragma unroll
  for (int i = 0; i < 4; i++) {
    #pragma unroll
    for (int j = 0; j < 4; j++) {
      const int col  = tileN + wN + j * 16 + lrow;
      const int row0 = tileM + wM + i * 16 + quad * 4;
      const float bv = bias ? bias[col] : 0.0f;
      float vals[4];
      #pragma unroll
      for (int r = 0; r < 4; r++) {
        float val = acc[i][j][r] + bv;
        if (relu) val = fmaxf(val, 0.0f);
        if (residf) val += residf[(size_t)(row0 + r) * N + col];
        vals[r] = val;
      }
      if (outq) {
        const int lcol = col & 1023;
        if (qkv_cat < 2) {
          #pragma unroll
          for (int r = 0; r < 4; r++)
            qk_out[(size_t)(row0 + r) * D_MODEL + lcol] = f2bf(vals[r]);
        } else {
          // vt[((b*NH+h)*DK+d)*SEQ + s]: b=row>>11, s=row&2047, h=lcol>>6, d=lcol&63
          union { int2 v; unsigned short u[4]; } pk;
          #pragma unroll
          for (int r = 0; r < 4; r++) pk.u[r] = f2bf(vals[r]);
          size_t tidx = (((size_t)(row0 >> 11) * NH + (lcol >> 6)) * DK + (lcol & 63)) * SEQ + (row0 & 2047);
          *(int2*)(outvt + tidx) = pk.v;
        }
      } else {
        #pragma unroll
        for (int r = 0; r < 4; r++) {
          const size_t idx = (size_t)(row0 + r) * N + col;
          if (outf) outf[idx] = vals[r];
          if (outb) outb[idx] = f2bf(vals[r]);
        }
      }
    }
  }
}

// ---------------- MFMA flash attention ----------------
// Block = 4 waves, 64 Q-rows of one (b,h). KV tiles of 64. Online softmax.
// Og may alias Qg (Q frags register-resident before any write).
#define AQT 64
#define AKT 64
#define LST 72   // LDS row stride (elems): b128 reads <=2-way conflicts
__global__ __launch_bounds__(256) void attn_mfma(
    const unsigned short* __restrict__ Qg,   // [B*S][D_MODEL] bf16
    const unsigned short* __restrict__ Kg,   // [B*S][D_MODEL] bf16
    const unsigned short* __restrict__ Vt,   // [(b*NH+h)*DK + d][SEQ] bf16 (transposed)
    const int* __restrict__ mask,            // [B*S]
    unsigned short* __restrict__ Og)
{
  __shared__ short Ks[AKT * LST];
  __shared__ short Vs[DK * LST];     // V^T tile: row=d, col=kv
  __shared__ short Ps[AQT * LST];
  __shared__ float maddf[AKT];

  const int bid = blockIdx.x;
  const int nqt = SEQ / AQT;          // 32
  const int b  = bid / (NH * nqt);
  const int h  = (bid / nqt) % NH;
  const int q0 = (bid % nqt) * AQT;
  const int t  = threadIdx.x;
  const int wv = t >> 6, lane = t & 63;
  const int quad = lane >> 4, l15 = lane & 15;

  bf16x8 qf0, qf1;
  {
    const unsigned short* qrow = Qg + (size_t)(b * SEQ + q0 + wv * 16 + l15) * D_MODEL + h * DK;
    qf0 = *(const bf16x8*)(qrow + quad * 8);
    qf1 = *(const bf16x8*)(qrow + 32 + quad * 8);
  }
  f32x4 oacc[4] = {};
  float m_run[4], l_run[4];
  #pragma unroll
  for (int r = 0; r < 4; r++) { m_run[r] = -1e30f; l_run[r] = 0.0f; }

  for (int kt = 0; kt < SEQ; kt += AKT) {
    #pragma unroll
    for (int it = 0; it < 2; it++) {
      int s = it * 256 + t;
      int row = s >> 3, c8 = (s & 7) * 8;
      *(int4*)&Ks[row * LST + c8] =
        *(const int4*)(Kg + (size_t)(b * SEQ + kt + row) * D_MODEL + h * DK + c8);
      *(int4*)&Vs[row * LST + c8] =
        *(const int4*)(Vt + ((size_t)(b * NH + h) * DK + row) * SEQ + kt + c8);
    }
    if (t < AKT) maddf[t] = mask[b * SEQ + kt + t] ? 0.0f : -1e9f;
    __syncthreads();

    f32x4 sc[4];
    #pragma unroll
    for (int ct = 0; ct < 4; ct++) {
      bf16x8 kb0 = *(const bf16x8*)&Ks[(ct * 16 + l15) * LST + quad * 8];
      bf16x8 kb1 = *(const bf16x8*)&Ks[(ct * 16 + l15) * LST + 32 + quad * 8];
      f32x4 a = {};
      a = __builtin_amdgcn_mfma_f32_16x16x32_bf16(qf0, kb0, a, 0, 0, 0);
      a = __builtin_amdgcn_mfma_f32_16x16x32_bf16(qf1, kb1, a, 0, 0, 0);
      float madd = maddf[ct * 16 + l15];
      #pragma unroll
      for (int r = 0; r < 4; r++) a[r] = a[r] * 0.125f + madd;
      sc[ct] = a;
    }
    float tmax[4];
    #pragma unroll
    for (int r = 0; r < 4; r++)
      tmax[r] = fmaxf(fmaxf(sc[0][r], sc[1][r]), fmaxf(sc[2][r], sc[3][r]));
    #pragma unroll
    for (int off = 1; off < 16; off <<= 1)
      #pragma unroll
      for (int r = 0; r < 4; r++)
        tmax[r] = fmaxf(tmax[r], __shfl_xor(tmax[r], off));
    float alpha[4];
    #pragma unroll
    for (int r = 0; r < 4; r++) {
      float mn = fmaxf(m_run[r], tmax[r]);
      alpha[r] = __expf(m_run[r] - mn);
      m_run[r] = mn;
    }
    float rs[4] = {0.f, 0.f, 0.f, 0.f};
    #pragma unroll
    for (int ct = 0; ct < 4; ct++)
      #pragma unroll
      for (int r = 0; r < 4; r++) {
        float p = __expf(sc[ct][r] - m_run[r]);
        rs[r] += p;
        Ps[(wv * 16 + quad * 4 + r) * LST + ct * 16 + l15] = (short)f2bf(p);
      }
    #pragma unroll
    for (int off = 1; off < 16; off <<= 1)
      #pragma unroll
      for (int r = 0; r < 4; r++)
        rs[r] += __shfl_xor(rs[r], off);
    #pragma unroll
    for (int r = 0; r < 4; r++) l_run[r] = l_run[r] * alpha[r] + rs[r];
    #pragma unroll
    for (int dt = 0; dt < 4; dt++)
      #pragma unroll
      for (int r = 0; r < 4; r++) oacc[dt][r] *= alpha[r];
    bf16x8 pf0 = *(const bf16x8*)&Ps[(wv * 16 + l15) * LST + quad * 8];
    bf16x8 pf1 = *(const bf16x8*)&Ps[(wv * 16 + l15) * LST + 32 + quad * 8];
    #pragma unroll
    for (int dt = 0; dt < 4; dt++) {
      bf16x8 vb0 = *(const bf16x8*)&Vs[(dt * 16 + l15) * LST + quad * 8];
      bf16x8 vb1 = *(const bf16x8*)&Vs[(dt * 16 + l15) * LST + 32 + quad * 8];
      oacc[dt] = __builtin_amdgcn_mfma_f32_16x16x32_bf16(pf0, vb0, oacc[dt], 0, 0, 0);
      oacc[dt] = __builtin_amdgcn_mfma_f32_16x16x32_bf16(pf1, vb1, oacc[dt], 0, 0, 0);
    }
    __syncthreads();
  }

  float linv[4];
  #pragma unroll
  for (int r = 0; r < 4; r++) linv[r] = 1.0f / l_run[r];
  #pragma unroll
  for (int dt = 0; dt < 4; dt++)
    #pragma unroll
    for (int r = 0; r < 4; r++)
      Og[(size_t)(b * SEQ + q0 + wv * 16 + quad * 4 + r) * D_MODEL + h * DK + dt * 16 + l15] =
        f2bf(oacc[dt][r] * linv[r]);
}

// ---------------- launch ----------------
// fp32 I/O. All GEMMs bf16 with just-in-time weight conversion. NO ws_size gate.
// ws high-water 48MB:
//   phase A: q [0,16)  k [16,32)  vt [32,48)
//   phase B (after attn): ao=q, wo16 -> [16,18) (k dead)
//   phase C (after o-proj): w1 -> [0,8), w2 -> [8,16) (ao dead); ln2 -> [32,48)
//            hff chunk -> [16,32)
// d_out as scratch: ln1b [0,16MB), wqkv16 [16,22MB); o-proj overwrites all with x1 fp32.
extern "C" void kernel_launch(void* const* d_in, const int* in_sizes, int n_in,
                              void* d_out, int out_size, void* d_ws, size_t ws_size,
                              hipStream_t stream)
{
  (void)in_sizes; (void)n_in; (void)out_size; (void)ws_size;
  const float* x   = (const float*)d_in[0];
  const int*   msk = (const int*)d_in[1];
  const float* w_q = (const float*)d_in[2];
  const float* w_k = (const float*)d_in[3];
  const float* w_v = (const float*)d_in[4];
  const float* w_o = (const float*)d_in[5];
  const float* w1  = (const float*)d_in[6];
  const float* b1  = (const float*)d_in[7];
  const float* w2  = (const float*)d_in[8];
  const float* b2  = (const float*)d_in[9];
  const float* g1  = (const float*)d_in[10];
  const float* be1 = (const float*)d_in[11];
  const float* g2  = (const float*)d_in[12];
  const float* be2 = (const float*)d_in[13];
  float* outf = (float*)d_out;

  char* ws = (char*)d_ws;
  const size_t MB = 1024 * 1024;
  unsigned short* q_b  = (unsigned short*)(ws + 0);        // 16MB -> ao
  unsigned short* k_b  = (unsigned short*)(ws + 16 * MB);  // 16MB -> wo16 -> hff chunk
  unsigned short* vt_b = (unsigned short*)(ws + 32 * MB);  // 16MB -> ln2b
  unsigned short* wo16 = (unsigned short*)(ws + 16 * MB);  // 2MB (k dead after attn)
  unsigned short* w116 = (unsigned short*)(ws + 0);        // 8MB (ao dead after o-proj)
  unsigned short* w216 = (unsigned short*)(ws + 8 * MB);   // 8MB
  unsigned short* ln2b = vt_b;                             // 16MB (vt dead after attn)
  unsigned short* hffc = k_b;                              // 16MB chunk

  unsigned short* ln1b   = (unsigned short*)d_out;                  // [0,16MB) of d_out
  unsigned short* wqkv16 = (unsigned short*)d_out + 8 * 1024 * 1024;// [16,22MB) of d_out

  dim3 blk(256);
  const int nw = D_MODEL * D_MODEL;  // 1M elems
  const int nf = DFF * D_MODEL;      // 4M elems

  // phase A: weights q|k|v -> fused bf16 [3072,1024] in d_out scratch; LN1
  cvt_f2b<<<nw / 1024, blk, 0, stream>>>(w_q, wqkv16, nw);
  cvt_f2b<<<nw / 1024, blk, 0, stream>>>(w_k, wqkv16 + nw, nw);
  cvt_f2b<<<nw / 1024, blk, 0, stream>>>(w_v, wqkv16 + 2 * nw, nw);
  ln_kernel<<<NROWS, blk, 0, stream>>>(x, g1, be1, ln1b);

  // fused QKV: [8192,1024] x [3072,1024]^T -> q, k, vt
  dim3 gqkv(3 * D_MODEL / 128, NROWS / 128);  // (24, 64) = 1536 blocks
  gemm_bt<<<gqkv, blk, 0, stream>>>(ln1b, wqkv16, D_MODEL, 3 * D_MODEL, nullptr, 0,
                                    nullptr, nullptr, nullptr, q_b, k_b, vt_b);

  // attention (output in-place over q)
  attn_mfma<<<BATCH * NH * (SEQ / AQT), blk, 0, stream>>>(q_b, k_b, vt_b, msk, q_b);

  // phase B: wo -> dead k region; o-proj + residual(x) -> x1 = d_out (fp32)
  cvt_f2b<<<nw / 1024, blk, 0, stream>>>(w_o, wo16, nw);
  dim3 gN1024(D_MODEL / 128, NROWS / 128);  // (8, 64)
  gemm_bt<<<gN1024, blk, 0, stream>>>(q_b, wo16, D_MODEL, D_MODEL, nullptr, 0, x,
                                      nullptr, outf, nullptr, nullptr, nullptr);

  // phase C: w1/w2 -> dead ao region; LN2 -> dead vt region; chunked FFN
  cvt_f2b<<<nf / 1024, blk, 0, stream>>>(w1, w116, nf);
  cvt_f2b<<<nf / 1024, blk, 0, stream>>>(w2, w216, nf);
  ln_kernel<<<NROWS, blk, 0, stream>>>(outf, g2, be2, ln2b);
  for (int c = 0; c < NCHUNK; c++) {
    const size_t ro = (size_t)c * CHUNK;
    dim3 g1c(DFF / 128,     CHUNK / 128);   // (32, 16)
    dim3 g2c(D_MODEL / 128, CHUNK / 128);   // (8, 16)
    gemm_bt<<<g1c, blk, 0, stream>>>(ln2b + ro * D_MODEL, w116, D_MODEL, DFF, b1, 1,
                                     nullptr, hffc, nullptr, nullptr, nullptr, nullptr);
    gemm_bt<<<g2c, blk, 0, stream>>>(hffc, w216, DFF, D_MODEL, b2, 0,
                                     outf + ro * D_MODEL, nullptr, outf + ro * D_MODEL,
                                     nullptr, nullptr, nullptr);
  }
}